// Round 10
// baseline (7598.257 us; speedup 1.0000x reference)
//
#include <hip/hip_runtime.h>
#include <hip/hip_bf16.h>
#include <math.h>

// ---------------------------------------------------------------------------
// SuperPoint point head, f64 end-to-end (NMS exact-equality requires score
// ordering identical to the float64 numpy reference).
// Round 10: weights register-double-buffered (chunk k+1's 18 A-operands
// loaded at the start of chunk k's phase, BEFORE the HBM act loads in the
// vmcnt FIFO) -> MFMA phase has zero global/LDS-write dependencies.
// r9's 27% bubble = first-MFMA wa-wait queued behind 6 HBM act loads.
// Accumulation order per output unchanged -> bit-identical scores.
// D fragment map stays RUNTIME-LEARNED via 2 probe MFMAs (round-6 win).
// ---------------------------------------------------------------------------

#define B_      16
#define HC      60
#define WC      80
#define PIX     (HC * WC)          // 4800
#define HF      480
#define WF      640
#define IMG     (HF * WF)          // 307200
#define NPIX    (B_ * IMG)         // 4915200

typedef double f64x4 __attribute__((ext_vector_type(4)));

__device__ __forceinline__ int clampi(int v, int lo, int hi) {
    return v < lo ? lo : (v > hi ? hi : v);
}

// ---------------------------------------------------------------------------
__global__ __launch_bounds__(256) void cvt_f32_f64(const float* __restrict__ s,
                                                   double* __restrict__ d, int n)
{
    int i = blockIdx.x * 256 + threadIdx.x;
    if (i < n) d[i] = (double)s[i];
}

// Weight pre-transform: w[oc][ic][3][3] f32 -> wT f64 laid out as
// [ocb][chk][dydx][ick][ocl]  (ocb=oc/16, ocl=oc%16, chk=ic/4, ick=ic%4)
__global__ __launch_bounds__(256) void prep_w(const float* __restrict__ w,
                                              double* __restrict__ wT,
                                              int CIN, int n)
{
    int i = blockIdx.x * 256 + threadIdx.x;
    if (i >= n) return;
    int cin9 = CIN * 9;
    int oc   = i / cin9;
    int rem  = i - oc * cin9;
    int ic   = rem / 9;
    int dydx = rem - ic * 9;
    size_t dst = ((size_t)((oc >> 4) * (CIN >> 2) + (ic >> 2)) * 9 + dydx) * 64
               + (ic & 3) * 16 + (oc & 15);
    wT[dst] = (double)w[i];
}

// ---------------------------------------------------------------------------
// conv 3x3 pad 1 + bias + ReLU via v_mfma_f64_16x16x4_f64.
// block 256 = 4 waves = (2 output rows) x (2 ocb-pairs); 64 oc per block.
// grid: (30 ytiles, COUT/64, G batches).
// Per 4-ic chunk (one barrier):
//   STOREC: ds_write act k+1 (regs -> buf^1)
//   issue weight loads k+1 -> regs (L2-hot, BEFORE act loads in vmcnt FIFO)
//   issue act loads k+2 -> regs (HBM; completes under the MFMA phase)
//   90 MFMAs: A from regs, B from LDS -- no global dependency
//   __syncthreads(); weight regs cur <- next
// ---------------------------------------------------------------------------
template <int CIN, typename TIN, bool RELU>
__global__ __launch_bounds__(256, 4) void conv3x3_mfma(
    const TIN* __restrict__ in,      // [G][CIN][60][80]
    const double* __restrict__ wT,   // transformed, see prep_w
    const double* __restrict__ bias, // [COUT]
    double* __restrict__ out)        // [G][COUT][60][80]
{
    const int COUT  = (CIN == 512) ? 256 : 128;
    const int NCH   = CIN / 4;
    const int ytile = blockIdx.x;          // 0..29 (2 rows each)
    const int ocq   = blockIdx.y;          // 64-oc group
    const int b     = blockIdx.z;
    const int tid   = threadIdx.x;
    const int wv    = tid >> 6;
    const int lane  = tid & 63;
    const int q     = lane >> 4;
    const int c     = lane & 15;
    const int wr    = wv & 1;              // wave's output row (0/1)
    const int wo    = wv >> 1;             // wave's ocb-pair (0/1)
    const int y0    = ytile * 2;
    const int y     = y0 + wr;

    in  += (size_t)b * CIN  * PIX;
    out += (size_t)b * COUT * PIX;

    // ---- self-learn the D fragment map: code(l,i) = 16*X + Y ---------------
    int rowL[4], colL[4];
    {
        f64x4 pr = (f64x4){0.0, 0.0, 0.0, 0.0};
        double a1 = (lane < 16) ? (double)(16 * lane) : 0.0;
        double b1 = (lane < 16) ? 1.0 : 0.0;
        pr = __builtin_amdgcn_mfma_f64_16x16x4f64(a1, b1, pr, 0, 0, 0);
        double a2 = (lane < 16) ? 1.0 : 0.0;
        double b2 = (lane < 16) ? (double)lane : 0.0;
        pr = __builtin_amdgcn_mfma_f64_16x16x4f64(a2, b2, pr, 0, 0, 0);
#pragma unroll
        for (int i = 0; i < 4; ++i) {
            int code = (int)pr[i];
            rowL[i] = (code >> 4) & 15;
            colL[i] = code & 15;
        }
    }

    // act double buffer: [2][4ic][4rows][82] = 2*1312 doubles = 20,992 B
    __shared__ double smem[2][1312];

    // this wave's two weight streams (global; L2-hot across blocks)
    const int ocb0 = ocq * 4 + wo * 2;
    const double* wA = wT + (size_t)ocb0 * NCH * 576;
    const double* wB = wT + (size_t)(ocb0 + 1) * NCH * 576;

    f64x4 acc[2][5];
#pragma unroll
    for (int o = 0; o < 2; ++o)
#pragma unroll
        for (int t = 0; t < 5; ++t) acc[o][t] = (f64x4){0.0, 0.0, 0.0, 0.0};

    const int bbase = q * 328 + wr * 82 + c;

    // ---- precompute act staging offsets (1312 elems, 6 per thread) ---------
    int aOff[6];
#pragma unroll
    for (int j = 0; j < 6; ++j) {
        int i   = tid + j * 256;
        int ick = i / 328;
        int rem = i - ick * 328;
        int ry  = rem / 82;
        int rx  = rem - ry * 82;
        int gy  = y0 - 1 + ry, gx = rx - 1;
        bool ok = (i < 1312) && ((unsigned)gy < (unsigned)HC) && ((unsigned)gx < (unsigned)WC);
        aOff[j] = ok ? (ick * PIX + gy * WC + gx) : -1;
    }

    double ra[6];
    double rwc0[9], rwc1[9];   // current chunk's weights (A-operands)
    double rwn0[9], rwn1[9];   // next chunk's weights

#define LOADC(ch)                                                              \
    {                                                                          \
        const int gbase = (ch) * 4 * PIX;                                      \
        _Pragma("unroll")                                                      \
        for (int j = 0; j < 6; ++j)                                            \
            ra[j] = (aOff[j] >= 0) ? (double)in[gbase + aOff[j]] : 0.0;        \
    }

#define STOREC(sel)                                                            \
    {                                                                          \
        double* dst = smem[sel];                                               \
        _Pragma("unroll")                                                      \
        for (int j = 0; j < 5; ++j) dst[tid + j * 256] = ra[j];                \
        if (tid < 32) dst[1280 + tid] = ra[5];                                 \
    }

#define LOADW(ch, r0, r1)                                                      \
    {                                                                          \
        const double* wa_ = wA + (size_t)(ch) * 576;                           \
        const double* wb_ = wB + (size_t)(ch) * 576;                           \
        _Pragma("unroll")                                                      \
        for (int d = 0; d < 9; ++d) {                                          \
            r0[d] = wa_[d * 64 + lane];                                        \
            r1[d] = wb_[d * 64 + lane];                                        \
        }                                                                      \
    }

    // prologue: weights(0) -> cur regs; act(0) -> LDS; act(1) -> regs
    LOADW(0, rwc0, rwc1);
    LOADC(0);
    STOREC(0);
    LOADC(1);
    __syncthreads();

    for (int chk = 0; chk < NCH; ++chk) {
        const int cur = chk & 1;
        if (chk + 1 < NCH) {
            STOREC(cur ^ 1);               // act k+1: regs -> LDS
            LOADW(chk + 1, rwn0, rwn1);    // weights k+1 (L2) BEFORE act loads
        }
        if (chk + 2 < NCH) LOADC(chk + 2); // act k+2 (HBM), completes under MFMA

        const double* act = smem[cur];
#pragma unroll
        for (int dy = 0; dy < 3; ++dy) {
#pragma unroll
            for (int dx = 0; dx < 3; ++dx) {
                const int d = dy * 3 + dx;
#pragma unroll
                for (int t = 0; t < 5; ++t) {
                    double bv = act[bbase + dy * 82 + t * 16 + dx];
                    acc[0][t] = __builtin_amdgcn_mfma_f64_16x16x4f64(rwc0[d], bv, acc[0][t], 0, 0, 0);
                    acc[1][t] = __builtin_amdgcn_mfma_f64_16x16x4f64(rwc1[d], bv, acc[1][t], 0, 0, 0);
                }
            }
        }

        if (chk + 1 < NCH) {
            __syncthreads();
#pragma unroll
            for (int d = 0; d < 9; ++d) { rwc0[d] = rwn0[d]; rwc1[d] = rwn1[d]; }
        }
    }
#undef LOADC
#undef STOREC
#undef LOADW

    // ---- epilogue: scatter via learned (X,Y), bias + ReLU ------------------
#pragma unroll
    for (int o = 0; o < 2; ++o) {
#pragma unroll
        for (int t = 0; t < 5; ++t) {
#pragma unroll
            for (int i = 0; i < 4; ++i) {
                const int oc = (ocb0 + o) * 16 + rowL[i];
                double v = acc[o][t][i] + bias[oc];
                if (RELU) v = fmax(v, 0.0);
                out[(size_t)oc * PIX + y * WC + t * 16 + colL[i]] = v;
            }
        }
    }
}

// ---------------------------------------------------------------------------
// conv1x1 (128->65) + softmax(65)[:64] + pixel-unshuffle.  grid (19, G).
// ---------------------------------------------------------------------------
__global__ __launch_bounds__(256) void conv1x1_softmax_f64(
    const double* __restrict__ h2,   // [G][128][4800]
    const double* __restrict__ wg,   // [65][128]
    const double* __restrict__ bg,   // [65]
    double* __restrict__ S)          // [G][480][640]
{
    int p = blockIdx.x * 256 + threadIdx.x;
    if (p >= PIX) return;
    const int b = blockIdx.y;
    const double* h2p = h2 + (size_t)b * 128 * PIX + p;
    double* Sb = S + (size_t)b * IMG;

    double l[65];
#pragma unroll
    for (int o = 0; o < 65; ++o) l[o] = bg[o];

    for (int icc = 0; icc < 128; icc += 8) {
        double h[8];
#pragma unroll
        for (int k = 0; k < 8; ++k) h[k] = h2p[(size_t)(icc + k) * PIX];
#pragma unroll
        for (int o = 0; o < 65; ++o) {
            const double* wp = wg + o * 128 + icc;
            l[o] += h[0] * wp[0] + h[1] * wp[1] + h[2] * wp[2] + h[3] * wp[3]
                  + h[4] * wp[4] + h[5] * wp[5] + h[6] * wp[6] + h[7] * wp[7];
        }
    }

    double m = l[0];
#pragma unroll
    for (int o = 1; o < 65; ++o) m = fmax(m, l[o]);
    double s = 0.0;
#pragma unroll
    for (int o = 0; o < 65; ++o) { l[o] = exp(l[o] - m); s += l[o]; }
    double inv = 1.0 / s;

    int y = p / WC, x = p % WC;
#pragma unroll
    for (int cy = 0; cy < 8; ++cy)
#pragma unroll
        for (int cx2 = 0; cx2 < 8; ++cx2)
            Sb[(y * 8 + cy) * WF + x * 8 + cx2] = l[cy * 8 + cx2] * inv;
}

// ---------------------------------------------------------------------------
// NMS passes on f64 scores (equality decisions must be f64-exact).
// ---------------------------------------------------------------------------
__global__ __launch_bounds__(256) void hmax9_f64(const double* __restrict__ in,
                                                 double* __restrict__ out)
{
    int p = blockIdx.x * 256 + threadIdx.x;
    int x = p % WF;
    const double* row = in + (p - x);
    double m = row[x];
#pragma unroll
    for (int d = 1; d <= 4; ++d) {
        m = fmax(m, row[clampi(x - d, 0, WF - 1)]);
        m = fmax(m, row[clampi(x + d, 0, WF - 1)]);
    }
    out[p] = m;
}

__global__ __launch_bounds__(256) void vmax9_eq(const double* __restrict__ T,
                                                const double* __restrict__ S,
                                                unsigned char* __restrict__ M)
{
    int p = blockIdx.x * 256 + threadIdx.x;
    int y = (p % IMG) / WF;
    double m = T[p];
#pragma unroll
    for (int d = 1; d <= 4; ++d) {
        m = fmax(m, T[p + (clampi(y - d, 0, HF - 1) - y) * WF]);
        m = fmax(m, T[p + (clampi(y + d, 0, HF - 1) - y) * WF]);
    }
    M[p] = (S[p] == m) ? (unsigned char)1 : (unsigned char)0;
}

__global__ __launch_bounds__(256) void hor9_u8(const unsigned char* __restrict__ in,
                                               unsigned char* __restrict__ out)
{
    int p = blockIdx.x * 256 + threadIdx.x;
    int x = p % WF;
    const unsigned char* row = in + (p - x);
    unsigned char m = row[x];
#pragma unroll
    for (int d = 1; d <= 4; ++d) {
        m = m | row[clampi(x - d, 0, WF - 1)];
        m = m | row[clampi(x + d, 0, WF - 1)];
    }
    out[p] = m;
}

__global__ __launch_bounds__(256) void vor9_sup(const unsigned char* __restrict__ T8,
                                                unsigned char* __restrict__ SUP)
{
    int p = blockIdx.x * 256 + threadIdx.x;
    int y = (p % IMG) / WF;
    unsigned char m = T8[p];
#pragma unroll
    for (int d = 1; d <= 4; ++d) {
        m = m | T8[p + (clampi(y - d, 0, HF - 1) - y) * WF];
        m = m | T8[p + (clampi(y + d, 0, HF - 1) - y) * WF];
    }
    SUP[p] = m;
}

// horizontal max of (SUP ? 0 : S)
__global__ __launch_bounds__(256) void hmax9_supp(const double* __restrict__ S,
                                                  const unsigned char* __restrict__ SUP,
                                                  double* __restrict__ T)
{
    int p = blockIdx.x * 256 + threadIdx.x;
    int x = p % WF;
    int base = p - x;
    double m = SUP[p] ? 0.0 : S[p];
#pragma unroll
    for (int d = 1; d <= 4; ++d) {
        int i1 = base + clampi(x - d, 0, WF - 1);
        int i2 = base + clampi(x + d, 0, WF - 1);
        m = fmax(m, SUP[i1] ? 0.0 : S[i1]);
        m = fmax(m, SUP[i2] ? 0.0 : S[i2]);
    }
    T[p] = m;
}

__global__ __launch_bounds__(256) void vmax9_newmask(const double* __restrict__ T,
                                                     const double* __restrict__ S,
                                                     const unsigned char* __restrict__ SUP,
                                                     unsigned char* __restrict__ M)
{
    int p = blockIdx.x * 256 + threadIdx.x;
    int y = (p % IMG) / WF;
    double m = T[p];
#pragma unroll
    for (int d = 1; d <= 4; ++d) {
        m = fmax(m, T[p + (clampi(y - d, 0, HF - 1) - y) * WF]);
        m = fmax(m, T[p + (clampi(y + d, 0, HF - 1) - y) * WF]);
    }
    unsigned char nw = (!SUP[p] && S[p] == m) ? 1 : 0;
    M[p] = M[p] | nw;
}

__global__ __launch_bounds__(256) void final_mask(const double* __restrict__ S,
                                                  const unsigned char* __restrict__ M,
                                                  float* __restrict__ out)
{
    int p = blockIdx.x * 256 + threadIdx.x;
    out[p] = M[p] ? (float)S[p] : 0.f;
}

// ---------------------------------------------------------------------------
extern "C" void kernel_launch(void* const* d_in, const int* in_sizes, int n_in,
                              void* d_out, int out_size, void* d_ws, size_t ws_size,
                              hipStream_t stream)
{
    const float* x   = (const float*)d_in[0];
    const float* wPa = (const float*)d_in[1];
    const float* bPa = (const float*)d_in[2];
    const float* wPd = (const float*)d_in[3];
    const float* bPd = (const float*)d_in[4];
    const float* wPg = (const float*)d_in[5];
    const float* bPg = (const float*)d_in[6];
    float* out = (float*)d_out;

    char* ws = (char*)d_ws;
    // ---- persistent / NMS-phase layout -------------------------------------
    double*        S   = (double*)(ws);                        // 39,321,600
    double*        T   = (double*)(ws + 39321600);             // 39,321,600
    unsigned char* M   = (unsigned char*)(ws + 78643200);      //  4,915,200
    unsigned char* SUP = (unsigned char*)(ws + 83558400);      //  4,915,200
    unsigned char* T8  = (unsigned char*)(ws + 88473600);      //  4,915,200
    // ---- conv-phase overlay (inside T region, dead until NMS) --------------
    double* w1t = (double*)(ws + 39321600);   // 256*512*9*8 = 9,437,184 (transformed)
    double* w2t = (double*)(ws + 48758784);   // 128*256*9*8 = 2,359,296 (transformed)
    double* wgd = (double*)(ws + 51118080);   // 65*128*8    =    66,560
    double* b1d = (double*)(ws + 51184640);   // 2,048
    double* b2d = (double*)(ws + 51186688);   // 1,024
    double* bgd = (double*)(ws + 51187712);   // 1,024 (pad)
    char*   hbase = ws + 51188736;            // batch-group h1/h2 area

    // largest batch-group G with 51,188,736 + G*14,745,600 <= ws_size
    // (G=16 confirmed on hardware in rounds 3-9)
    int G = 1;
    for (int g = 16; g >= 1; g >>= 1) {
        if ((size_t)51188736 + (size_t)g * 14745600 <= ws_size) { G = g; break; }
    }

    // weights -> f64, mfma layout for 3x3 convs
    prep_w<<<(1179648 + 255) / 256, 256, 0, stream>>>(wPa, w1t, 512, 1179648);
    prep_w<<<(294912 + 255) / 256, 256, 0, stream>>>(wPd, w2t, 256, 294912);
    cvt_f32_f64<<<(8320 + 255) / 256, 256, 0, stream>>>(wPg, wgd, 8320);
    cvt_f32_f64<<<1, 256, 0, stream>>>(bPa, b1d, 256);
    cvt_f32_f64<<<1, 256, 0, stream>>>(bPd, b2d, 128);
    cvt_f32_f64<<<1, 256, 0, stream>>>(bPg, bgd, 65);

    for (int bg0 = 0; bg0 < B_; bg0 += G) {
        int Gc = (bg0 + G <= B_) ? G : (B_ - bg0);
        double* h1s = (double*)hbase;                              // Gc*256*4800 f64
        double* h2s = (double*)(hbase + (size_t)G * 9830400);      // Gc*128*4800 f64
        const float* xb = x + (size_t)bg0 * 512 * PIX;
        conv3x3_mfma<512, float, true><<<dim3(30, 4, Gc), 256, 0, stream>>>(xb, w1t, b1d, h1s);
        conv3x3_mfma<256, double, true><<<dim3(30, 2, Gc), 256, 0, stream>>>(h1s, w2t, b2d, h2s);
        conv1x1_softmax_f64<<<dim3(19, Gc), 256, 0, stream>>>(h2s, wgd, bgd, S + (size_t)bg0 * IMG);
    }

    const int NB = NPIX / 256;  // 19200
    hmax9_f64<<<NB, 256, 0, stream>>>(S, T);
    vmax9_eq<<<NB, 256, 0, stream>>>(T, S, M);
    for (int it = 0; it < 2; ++it) {
        hor9_u8<<<NB, 256, 0, stream>>>(M, T8);
        vor9_sup<<<NB, 256, 0, stream>>>(T8, SUP);
        hmax9_supp<<<NB, 256, 0, stream>>>(S, SUP, T);
        vmax9_newmask<<<NB, 256, 0, stream>>>(T, S, SUP, M);
    }
    final_mask<<<NB, 256, 0, stream>>>(S, M, out);
}

// Round 11
// 4691.362 us; speedup vs baseline: 1.6196x; 1.6196x over previous
//
#include <hip/hip_runtime.h>
#include <hip/hip_bf16.h>
#include <math.h>

// ---------------------------------------------------------------------------
// SuperPoint point head, f64 end-to-end (NMS exact-equality requires score
// ordering identical to the float64 numpy reference).
// Round 11: r9 base + vmcnt-FIFO fix at r9's register budget.
//   Per chunk, issue the 18 L2-hot weight loads FIRST, then the 6 HBM act
//   loads: the MFMA phase's weight-wait becomes vmcnt(6) (~200cy, covered by
//   the interleaved ds_writes) instead of draining 900cy HBM loads.
//   Single weight buffer (+36 VGPR over r9's 84 -> ~130 < 170 cap, no spill;
//   r10's launch_bounds(256,4) cap=128 caused a 21GB/dispatch scratch-spill
//   disaster -- VGPR+AGPR are a unified file on gfx950, acc counts too).
// Accumulation order per output unchanged -> bit-identical scores.
// D fragment map stays RUNTIME-LEARNED via 2 probe MFMAs (round-6 win).
// ---------------------------------------------------------------------------

#define B_      16
#define HC      60
#define WC      80
#define PIX     (HC * WC)          // 4800
#define HF      480
#define WF      640
#define IMG     (HF * WF)          // 307200
#define NPIX    (B_ * IMG)         // 4915200

typedef double f64x4 __attribute__((ext_vector_type(4)));

__device__ __forceinline__ int clampi(int v, int lo, int hi) {
    return v < lo ? lo : (v > hi ? hi : v);
}

// ---------------------------------------------------------------------------
__global__ __launch_bounds__(256) void cvt_f32_f64(const float* __restrict__ s,
                                                   double* __restrict__ d, int n)
{
    int i = blockIdx.x * 256 + threadIdx.x;
    if (i < n) d[i] = (double)s[i];
}

// Weight pre-transform: w[oc][ic][3][3] f32 -> wT f64 laid out as
// [ocb][chk][dydx][ick][ocl]  (ocb=oc/16, ocl=oc%16, chk=ic/4, ick=ic%4)
__global__ __launch_bounds__(256) void prep_w(const float* __restrict__ w,
                                              double* __restrict__ wT,
                                              int CIN, int n)
{
    int i = blockIdx.x * 256 + threadIdx.x;
    if (i >= n) return;
    int cin9 = CIN * 9;
    int oc   = i / cin9;
    int rem  = i - oc * cin9;
    int ic   = rem / 9;
    int dydx = rem - ic * 9;
    size_t dst = ((size_t)((oc >> 4) * (CIN >> 2) + (ic >> 2)) * 9 + dydx) * 64
               + (ic & 3) * 16 + (oc & 15);
    wT[dst] = (double)w[i];
}

// ---------------------------------------------------------------------------
// conv 3x3 pad 1 + bias + ReLU via v_mfma_f64_16x16x4_f64.
// block 256 = 4 waves = (2 output rows) x (2 ocb-pairs); 64 oc per block.
// grid: (30 ytiles, COUT/64, G batches).
// Per 4-ic chunk (one barrier), program order = vmcnt FIFO order:
//   LOADW(chk): 18 weight loads (L2-hot)  <- FIRST in FIFO
//   STOREC: ds_write act k+1 (regs -> buf^1), covers weight L2 latency
//   LOADC(k+2): 6 HBM act loads           <- behind weights in FIFO
//   90 MFMAs: A waits vmcnt(6) (weights only), B from LDS
//   __syncthreads()
// ---------------------------------------------------------------------------
template <int CIN, typename TIN, bool RELU>
__global__ __launch_bounds__(256, 3) void conv3x3_mfma(
    const TIN* __restrict__ in,      // [G][CIN][60][80]
    const double* __restrict__ wT,   // transformed, see prep_w
    const double* __restrict__ bias, // [COUT]
    double* __restrict__ out)        // [G][COUT][60][80]
{
    const int COUT  = (CIN == 512) ? 256 : 128;
    const int NCH   = CIN / 4;
    const int ytile = blockIdx.x;          // 0..29 (2 rows each)
    const int ocq   = blockIdx.y;          // 64-oc group
    const int b     = blockIdx.z;
    const int tid   = threadIdx.x;
    const int wv    = tid >> 6;
    const int lane  = tid & 63;
    const int q     = lane >> 4;
    const int c     = lane & 15;
    const int wr    = wv & 1;              // wave's output row (0/1)
    const int wo    = wv >> 1;             // wave's ocb-pair (0/1)
    const int y0    = ytile * 2;
    const int y     = y0 + wr;

    in  += (size_t)b * CIN  * PIX;
    out += (size_t)b * COUT * PIX;

    // ---- self-learn the D fragment map: code(l,i) = 16*X + Y ---------------
    int rowL[4], colL[4];
    {
        f64x4 pr = (f64x4){0.0, 0.0, 0.0, 0.0};
        double a1 = (lane < 16) ? (double)(16 * lane) : 0.0;
        double b1 = (lane < 16) ? 1.0 : 0.0;
        pr = __builtin_amdgcn_mfma_f64_16x16x4f64(a1, b1, pr, 0, 0, 0);
        double a2 = (lane < 16) ? 1.0 : 0.0;
        double b2 = (lane < 16) ? (double)lane : 0.0;
        pr = __builtin_amdgcn_mfma_f64_16x16x4f64(a2, b2, pr, 0, 0, 0);
#pragma unroll
        for (int i = 0; i < 4; ++i) {
            int code = (int)pr[i];
            rowL[i] = (code >> 4) & 15;
            colL[i] = code & 15;
        }
    }

    // act double buffer: [2][4ic][4rows][82] = 2*1312 doubles = 20,992 B
    __shared__ double smem[2][1312];

    // this wave's two weight streams (global; L2-hot across blocks)
    const int ocb0 = ocq * 4 + wo * 2;
    const double* wA = wT + (size_t)ocb0 * NCH * 576;
    const double* wB = wT + (size_t)(ocb0 + 1) * NCH * 576;

    f64x4 acc[2][5];
#pragma unroll
    for (int o = 0; o < 2; ++o)
#pragma unroll
        for (int t = 0; t < 5; ++t) acc[o][t] = (f64x4){0.0, 0.0, 0.0, 0.0};

    const int bbase = q * 328 + wr * 82 + c;

    // ---- precompute act staging offsets (1312 elems, 6 per thread) ---------
    int aOff[6];
#pragma unroll
    for (int j = 0; j < 6; ++j) {
        int i   = tid + j * 256;
        int ick = i / 328;
        int rem = i - ick * 328;
        int ry  = rem / 82;
        int rx  = rem - ry * 82;
        int gy  = y0 - 1 + ry, gx = rx - 1;
        bool ok = (i < 1312) && ((unsigned)gy < (unsigned)HC) && ((unsigned)gx < (unsigned)WC);
        aOff[j] = ok ? (ick * PIX + gy * WC + gx) : -1;
    }

    double ra[6];
    double rw0[9], rw1[9];   // current chunk's A-operands (single buffer)

#define LOADW(ch)                                                              \
    {                                                                          \
        const double* wa_ = wA + (size_t)(ch) * 576;                           \
        const double* wb_ = wB + (size_t)(ch) * 576;                           \
        _Pragma("unroll")                                                      \
        for (int d = 0; d < 9; ++d) {                                          \
            rw0[d] = wa_[d * 64 + lane];                                       \
            rw1[d] = wb_[d * 64 + lane];                                       \
        }                                                                      \
    }

#define LOADC(ch)                                                              \
    {                                                                          \
        const int gbase = (ch) * 4 * PIX;                                      \
        _Pragma("unroll")                                                      \
        for (int j = 0; j < 6; ++j)                                            \
            ra[j] = (aOff[j] >= 0) ? (double)in[gbase + aOff[j]] : 0.0;        \
    }

#define STOREC(sel)                                                            \
    {                                                                          \
        double* dst = smem[sel];                                               \
        _Pragma("unroll")                                                      \
        for (int j = 0; j < 5; ++j) dst[tid + j * 256] = ra[j];                \
        if (tid < 32) dst[1280 + tid] = ra[5];                                 \
    }

    // prologue: act(0) -> LDS; act(1) -> regs
    LOADC(0);
    STOREC(0);
    LOADC(1);
    __syncthreads();

    for (int chk = 0; chk < NCH; ++chk) {
        const int cur = chk & 1;
        LOADW(chk);                        // 18 L2 loads, FIRST in vmcnt FIFO
        if (chk + 1 < NCH) STOREC(cur ^ 1);// ds_writes cover weight L2 latency
        if (chk + 2 < NCH) LOADC(chk + 2); // 6 HBM loads, behind weights

        const double* act = smem[cur];
#pragma unroll
        for (int dy = 0; dy < 3; ++dy) {
#pragma unroll
            for (int dx = 0; dx < 3; ++dx) {
                const int d = dy * 3 + dx;
#pragma unroll
                for (int t = 0; t < 5; ++t) {
                    double bv = act[bbase + dy * 82 + t * 16 + dx];
                    acc[0][t] = __builtin_amdgcn_mfma_f64_16x16x4f64(rw0[d], bv, acc[0][t], 0, 0, 0);
                    acc[1][t] = __builtin_amdgcn_mfma_f64_16x16x4f64(rw1[d], bv, acc[1][t], 0, 0, 0);
                }
            }
        }
        if (chk + 1 < NCH) __syncthreads();
    }
#undef LOADW
#undef LOADC
#undef STOREC

    // ---- epilogue: scatter via learned (X,Y), bias + ReLU ------------------
#pragma unroll
    for (int o = 0; o < 2; ++o) {
#pragma unroll
        for (int t = 0; t < 5; ++t) {
#pragma unroll
            for (int i = 0; i < 4; ++i) {
                const int oc = (ocb0 + o) * 16 + rowL[i];
                double v = acc[o][t][i] + bias[oc];
                if (RELU) v = fmax(v, 0.0);
                out[(size_t)oc * PIX + y * WC + t * 16 + colL[i]] = v;
            }
        }
    }
}

// ---------------------------------------------------------------------------
// conv1x1 (128->65) + softmax(65)[:64] + pixel-unshuffle.  grid (19, G).
// ---------------------------------------------------------------------------
__global__ __launch_bounds__(256) void conv1x1_softmax_f64(
    const double* __restrict__ h2,   // [G][128][4800]
    const double* __restrict__ wg,   // [65][128]
    const double* __restrict__ bg,   // [65]
    double* __restrict__ S)          // [G][480][640]
{
    int p = blockIdx.x * 256 + threadIdx.x;
    if (p >= PIX) return;
    const int b = blockIdx.y;
    const double* h2p = h2 + (size_t)b * 128 * PIX + p;
    double* Sb = S + (size_t)b * IMG;

    double l[65];
#pragma unroll
    for (int o = 0; o < 65; ++o) l[o] = bg[o];

    for (int icc = 0; icc < 128; icc += 8) {
        double h[8];
#pragma unroll
        for (int k = 0; k < 8; ++k) h[k] = h2p[(size_t)(icc + k) * PIX];
#pragma unroll
        for (int o = 0; o < 65; ++o) {
            const double* wp = wg + o * 128 + icc;
            l[o] += h[0] * wp[0] + h[1] * wp[1] + h[2] * wp[2] + h[3] * wp[3]
                  + h[4] * wp[4] + h[5] * wp[5] + h[6] * wp[6] + h[7] * wp[7];
        }
    }

    double m = l[0];
#pragma unroll
    for (int o = 1; o < 65; ++o) m = fmax(m, l[o]);
    double s = 0.0;
#pragma unroll
    for (int o = 0; o < 65; ++o) { l[o] = exp(l[o] - m); s += l[o]; }
    double inv = 1.0 / s;

    int y = p / WC, x = p % WC;
#pragma unroll
    for (int cy = 0; cy < 8; ++cy)
#pragma unroll
        for (int cx2 = 0; cx2 < 8; ++cx2)
            Sb[(y * 8 + cy) * WF + x * 8 + cx2] = l[cy * 8 + cx2] * inv;
}

// ---------------------------------------------------------------------------
// NMS passes on f64 scores (equality decisions must be f64-exact).
// ---------------------------------------------------------------------------
__global__ __launch_bounds__(256) void hmax9_f64(const double* __restrict__ in,
                                                 double* __restrict__ out)
{
    int p = blockIdx.x * 256 + threadIdx.x;
    int x = p % WF;
    const double* row = in + (p - x);
    double m = row[x];
#pragma unroll
    for (int d = 1; d <= 4; ++d) {
        m = fmax(m, row[clampi(x - d, 0, WF - 1)]);
        m = fmax(m, row[clampi(x + d, 0, WF - 1)]);
    }
    out[p] = m;
}

__global__ __launch_bounds__(256) void vmax9_eq(const double* __restrict__ T,
                                                const double* __restrict__ S,
                                                unsigned char* __restrict__ M)
{
    int p = blockIdx.x * 256 + threadIdx.x;
    int y = (p % IMG) / WF;
    double m = T[p];
#pragma unroll
    for (int d = 1; d <= 4; ++d) {
        m = fmax(m, T[p + (clampi(y - d, 0, HF - 1) - y) * WF]);
        m = fmax(m, T[p + (clampi(y + d, 0, HF - 1) - y) * WF]);
    }
    M[p] = (S[p] == m) ? (unsigned char)1 : (unsigned char)0;
}

__global__ __launch_bounds__(256) void hor9_u8(const unsigned char* __restrict__ in,
                                               unsigned char* __restrict__ out)
{
    int p = blockIdx.x * 256 + threadIdx.x;
    int x = p % WF;
    const unsigned char* row = in + (p - x);
    unsigned char m = row[x];
#pragma unroll
    for (int d = 1; d <= 4; ++d) {
        m = m | row[clampi(x - d, 0, WF - 1)];
        m = m | row[clampi(x + d, 0, WF - 1)];
    }
    out[p] = m;
}

__global__ __launch_bounds__(256) void vor9_sup(const unsigned char* __restrict__ T8,
                                                unsigned char* __restrict__ SUP)
{
    int p = blockIdx.x * 256 + threadIdx.x;
    int y = (p % IMG) / WF;
    unsigned char m = T8[p];
#pragma unroll
    for (int d = 1; d <= 4; ++d) {
        m = m | T8[p + (clampi(y - d, 0, HF - 1) - y) * WF];
        m = m | T8[p + (clampi(y + d, 0, HF - 1) - y) * WF];
    }
    SUP[p] = m;
}

// horizontal max of (SUP ? 0 : S)
__global__ __launch_bounds__(256) void hmax9_supp(const double* __restrict__ S,
                                                  const unsigned char* __restrict__ SUP,
                                                  double* __restrict__ T)
{
    int p = blockIdx.x * 256 + threadIdx.x;
    int x = p % WF;
    int base = p - x;
    double m = SUP[p] ? 0.0 : S[p];
#pragma unroll
    for (int d = 1; d <= 4; ++d) {
        int i1 = base + clampi(x - d, 0, WF - 1);
        int i2 = base + clampi(x + d, 0, WF - 1);
        m = fmax(m, SUP[i1] ? 0.0 : S[i1]);
        m = fmax(m, SUP[i2] ? 0.0 : S[i2]);
    }
    T[p] = m;
}

__global__ __launch_bounds__(256) void vmax9_newmask(const double* __restrict__ T,
                                                     const double* __restrict__ S,
                                                     const unsigned char* __restrict__ SUP,
                                                     unsigned char* __restrict__ M)
{
    int p = blockIdx.x * 256 + threadIdx.x;
    int y = (p % IMG) / WF;
    double m = T[p];
#pragma unroll
    for (int d = 1; d <= 4; ++d) {
        m = fmax(m, T[p + (clampi(y - d, 0, HF - 1) - y) * WF]);
        m = fmax(m, T[p + (clampi(y + d, 0, HF - 1) - y) * WF]);
    }
    unsigned char nw = (!SUP[p] && S[p] == m) ? 1 : 0;
    M[p] = M[p] | nw;
}

__global__ __launch_bounds__(256) void final_mask(const double* __restrict__ S,
                                                  const unsigned char* __restrict__ M,
                                                  float* __restrict__ out)
{
    int p = blockIdx.x * 256 + threadIdx.x;
    out[p] = M[p] ? (float)S[p] : 0.f;
}

// ---------------------------------------------------------------------------
extern "C" void kernel_launch(void* const* d_in, const int* in_sizes, int n_in,
                              void* d_out, int out_size, void* d_ws, size_t ws_size,
                              hipStream_t stream)
{
    const float* x   = (const float*)d_in[0];
    const float* wPa = (const float*)d_in[1];
    const float* bPa = (const float*)d_in[2];
    const float* wPd = (const float*)d_in[3];
    const float* bPd = (const float*)d_in[4];
    const float* wPg = (const float*)d_in[5];
    const float* bPg = (const float*)d_in[6];
    float* out = (float*)d_out;

    char* ws = (char*)d_ws;
    // ---- persistent / NMS-phase layout -------------------------------------
    double*        S   = (double*)(ws);                        // 39,321,600
    double*        T   = (double*)(ws + 39321600);             // 39,321,600
    unsigned char* M   = (unsigned char*)(ws + 78643200);      //  4,915,200
    unsigned char* SUP = (unsigned char*)(ws + 83558400);      //  4,915,200
    unsigned char* T8  = (unsigned char*)(ws + 88473600);      //  4,915,200
    // ---- conv-phase overlay (inside T region, dead until NMS) --------------
    double* w1t = (double*)(ws + 39321600);   // 256*512*9*8 = 9,437,184 (transformed)
    double* w2t = (double*)(ws + 48758784);   // 128*256*9*8 = 2,359,296 (transformed)
    double* wgd = (double*)(ws + 51118080);   // 65*128*8    =    66,560
    double* b1d = (double*)(ws + 51184640);   // 2,048
    double* b2d = (double*)(ws + 51186688);   // 1,024
    double* bgd = (double*)(ws + 51187712);   // 1,024 (pad)
    char*   hbase = ws + 51188736;            // batch-group h1/h2 area

    // largest batch-group G with 51,188,736 + G*14,745,600 <= ws_size
    // (G=16 confirmed on hardware in rounds 3-10)
    int G = 1;
    for (int g = 16; g >= 1; g >>= 1) {
        if ((size_t)51188736 + (size_t)g * 14745600 <= ws_size) { G = g; break; }
    }

    // weights -> f64, mfma layout for 3x3 convs
    prep_w<<<(1179648 + 255) / 256, 256, 0, stream>>>(wPa, w1t, 512, 1179648);
    prep_w<<<(294912 + 255) / 256, 256, 0, stream>>>(wPd, w2t, 256, 294912);
    cvt_f32_f64<<<(8320 + 255) / 256, 256, 0, stream>>>(wPg, wgd, 8320);
    cvt_f32_f64<<<1, 256, 0, stream>>>(bPa, b1d, 256);
    cvt_f32_f64<<<1, 256, 0, stream>>>(bPd, b2d, 128);
    cvt_f32_f64<<<1, 256, 0, stream>>>(bPg, bgd, 65);

    for (int bg0 = 0; bg0 < B_; bg0 += G) {
        int Gc = (bg0 + G <= B_) ? G : (B_ - bg0);
        double* h1s = (double*)hbase;                              // Gc*256*4800 f64
        double* h2s = (double*)(hbase + (size_t)G * 9830400);      // Gc*128*4800 f64
        const float* xb = x + (size_t)bg0 * 512 * PIX;
        conv3x3_mfma<512, float, true><<<dim3(30, 4, Gc), 256, 0, stream>>>(xb, w1t, b1d, h1s);
        conv3x3_mfma<256, double, true><<<dim3(30, 2, Gc), 256, 0, stream>>>(h1s, w2t, b2d, h2s);
        conv1x1_softmax_f64<<<dim3(19, Gc), 256, 0, stream>>>(h2s, wgd, bgd, S + (size_t)bg0 * IMG);
    }

    const int NB = NPIX / 256;  // 19200
    hmax9_f64<<<NB, 256, 0, stream>>>(S, T);
    vmax9_eq<<<NB, 256, 0, stream>>>(T, S, M);
    for (int it = 0; it < 2; ++it) {
        hor9_u8<<<NB, 256, 0, stream>>>(M, T8);
        vor9_sup<<<NB, 256, 0, stream>>>(T8, SUP);
        hmax9_supp<<<NB, 256, 0, stream>>>(S, SUP, T);
        vmax9_newmask<<<NB, 256, 0, stream>>>(T, S, SUP, M);
    }
    final_mask<<<NB, 256, 0, stream>>>(S, M, out);
}

// Round 12
// 4382.891 us; speedup vs baseline: 1.7336x; 1.0704x over previous
//
#include <hip/hip_runtime.h>
#include <hip/hip_bf16.h>
#include <math.h>

// ---------------------------------------------------------------------------
// SuperPoint point head, f64 end-to-end (NMS exact-equality requires score
// ordering identical to the float64 numpy reference).
// Round 12: r9's exact conv kernel (best so far: 3.35ms @ 73% MfmaUtil) with
// __launch_bounds__(256,4): 4 co-resident blocks/CU at staggered barrier
// phases fill each other's staging bubbles.  VGPR cap 128 >= r9's 84 -> no
// spill (r10's spill disaster was the weight-dbuf variant needing ~140).
// Source-level load reordering (r11) was proven ineffective: compiler owns
// the vmcnt FIFO (VGPR stayed 84, perf unchanged).
// Accumulation order per output unchanged -> bit-identical scores.
// D fragment map stays RUNTIME-LEARNED via 2 probe MFMAs (round-6 win).
// ---------------------------------------------------------------------------

#define B_      16
#define HC      60
#define WC      80
#define PIX     (HC * WC)          // 4800
#define HF      480
#define WF      640
#define IMG     (HF * WF)          // 307200
#define NPIX    (B_ * IMG)         // 4915200

typedef double f64x4 __attribute__((ext_vector_type(4)));

__device__ __forceinline__ int clampi(int v, int lo, int hi) {
    return v < lo ? lo : (v > hi ? hi : v);
}

// ---------------------------------------------------------------------------
__global__ __launch_bounds__(256) void cvt_f32_f64(const float* __restrict__ s,
                                                   double* __restrict__ d, int n)
{
    int i = blockIdx.x * 256 + threadIdx.x;
    if (i < n) d[i] = (double)s[i];
}

// Weight pre-transform: w[oc][ic][3][3] f32 -> wT f64 laid out as
// [ocb][chk][dydx][ick][ocl]  (ocb=oc/16, ocl=oc%16, chk=ic/4, ick=ic%4)
__global__ __launch_bounds__(256) void prep_w(const float* __restrict__ w,
                                              double* __restrict__ wT,
                                              int CIN, int n)
{
    int i = blockIdx.x * 256 + threadIdx.x;
    if (i >= n) return;
    int cin9 = CIN * 9;
    int oc   = i / cin9;
    int rem  = i - oc * cin9;
    int ic   = rem / 9;
    int dydx = rem - ic * 9;
    size_t dst = ((size_t)((oc >> 4) * (CIN >> 2) + (ic >> 2)) * 9 + dydx) * 64
               + (ic & 3) * 16 + (oc & 15);
    wT[dst] = (double)w[i];
}

// ---------------------------------------------------------------------------
// conv 3x3 pad 1 + bias + ReLU via v_mfma_f64_16x16x4_f64.
// block 256 = 4 waves = (2 output rows) x (2 ocb-pairs); 64 oc per block.
// grid: (30 ytiles, COUT/64, G batches).
// Per 4-ic chunk (one barrier): ds_write next act; issue act loads k+2;
// A-operands from GLOBAL (L2-hot) inside the unrolled dydx loop; 90 MFMAs.
// 4 blocks/CU co-resident (launch_bounds(256,4)) fill barrier bubbles.
// ---------------------------------------------------------------------------
template <int CIN, typename TIN, bool RELU>
__global__ __launch_bounds__(256, 4) void conv3x3_mfma(
    const TIN* __restrict__ in,      // [G][CIN][60][80]
    const double* __restrict__ wT,   // transformed, see prep_w
    const double* __restrict__ bias, // [COUT]
    double* __restrict__ out)        // [G][COUT][60][80]
{
    const int COUT  = (CIN == 512) ? 256 : 128;
    const int NCH   = CIN / 4;
    const int ytile = blockIdx.x;          // 0..29 (2 rows each)
    const int ocq   = blockIdx.y;          // 64-oc group
    const int b     = blockIdx.z;
    const int tid   = threadIdx.x;
    const int wv    = tid >> 6;
    const int lane  = tid & 63;
    const int q     = lane >> 4;
    const int c     = lane & 15;
    const int wr    = wv & 1;              // wave's output row (0/1)
    const int wo    = wv >> 1;             // wave's ocb-pair (0/1)
    const int y0    = ytile * 2;
    const int y     = y0 + wr;

    in  += (size_t)b * CIN  * PIX;
    out += (size_t)b * COUT * PIX;

    // ---- self-learn the D fragment map: code(l,i) = 16*X + Y ---------------
    int rowL[4], colL[4];
    {
        f64x4 pr = (f64x4){0.0, 0.0, 0.0, 0.0};
        double a1 = (lane < 16) ? (double)(16 * lane) : 0.0;
        double b1 = (lane < 16) ? 1.0 : 0.0;
        pr = __builtin_amdgcn_mfma_f64_16x16x4f64(a1, b1, pr, 0, 0, 0);
        double a2 = (lane < 16) ? 1.0 : 0.0;
        double b2 = (lane < 16) ? (double)lane : 0.0;
        pr = __builtin_amdgcn_mfma_f64_16x16x4f64(a2, b2, pr, 0, 0, 0);
#pragma unroll
        for (int i = 0; i < 4; ++i) {
            int code = (int)pr[i];
            rowL[i] = (code >> 4) & 15;
            colL[i] = code & 15;
        }
    }

    // act double buffer: [2][4ic][4rows][82] = 2*1312 doubles = 20,992 B
    __shared__ double smem[2][1312];

    // this wave's two weight streams (global; shared by many blocks -> L2-hot)
    const int ocb0 = ocq * 4 + wo * 2;
    const double* wA = wT + (size_t)ocb0 * NCH * 576;
    const double* wB = wT + (size_t)(ocb0 + 1) * NCH * 576;

    f64x4 acc[2][5];
#pragma unroll
    for (int o = 0; o < 2; ++o)
#pragma unroll
        for (int t = 0; t < 5; ++t) acc[o][t] = (f64x4){0.0, 0.0, 0.0, 0.0};

    const int bbase = q * 328 + wr * 82 + c;

    // ---- precompute act staging offsets (1312 elems, 6 per thread) ---------
    int aOff[6];
#pragma unroll
    for (int j = 0; j < 6; ++j) {
        int i   = tid + j * 256;
        int ick = i / 328;
        int rem = i - ick * 328;
        int ry  = rem / 82;
        int rx  = rem - ry * 82;
        int gy  = y0 - 1 + ry, gx = rx - 1;
        bool ok = (i < 1312) && ((unsigned)gy < (unsigned)HC) && ((unsigned)gx < (unsigned)WC);
        aOff[j] = ok ? (ick * PIX + gy * WC + gx) : -1;
    }

    double ra[6];

#define LOADC(ch)                                                              \
    {                                                                          \
        const int gbase = (ch) * 4 * PIX;                                      \
        _Pragma("unroll")                                                      \
        for (int j = 0; j < 6; ++j)                                            \
            ra[j] = (aOff[j] >= 0) ? (double)in[gbase + aOff[j]] : 0.0;        \
    }

#define STOREC(sel)                                                            \
    {                                                                          \
        double* dst = smem[sel];                                               \
        _Pragma("unroll")                                                      \
        for (int j = 0; j < 5; ++j) dst[tid + j * 256] = ra[j];                \
        if (tid < 32) dst[1280 + tid] = ra[5];                                 \
    }

    LOADC(0);
    STOREC(0);
    LOADC(1);
    __syncthreads();

    for (int chk = 0; chk < NCH; ++chk) {
        const int cur = chk & 1;
        if (chk + 1 < NCH) STOREC(cur ^ 1);   // regs hold chunk chk+1
        if (chk + 2 < NCH) LOADC(chk + 2);    // completes under MFMA phase

        const double* wa  = wA + (size_t)chk * 576;
        const double* wb  = wB + (size_t)chk * 576;
        const double* act = smem[cur];

#pragma unroll
        for (int dy = 0; dy < 3; ++dy) {
#pragma unroll
            for (int dx = 0; dx < 3; ++dx) {
                const int d = dy * 3 + dx;
                double a0 = wa[d * 64 + lane];
                double a1 = wb[d * 64 + lane];
#pragma unroll
                for (int t = 0; t < 5; ++t) {
                    double bv = act[bbase + dy * 82 + t * 16 + dx];
                    acc[0][t] = __builtin_amdgcn_mfma_f64_16x16x4f64(a0, bv, acc[0][t], 0, 0, 0);
                    acc[1][t] = __builtin_amdgcn_mfma_f64_16x16x4f64(a1, bv, acc[1][t], 0, 0, 0);
                }
            }
        }
        if (chk + 1 < NCH) __syncthreads();
    }
#undef LOADC
#undef STOREC

    // ---- epilogue: scatter via learned (X,Y), bias + ReLU ------------------
#pragma unroll
    for (int o = 0; o < 2; ++o) {
#pragma unroll
        for (int t = 0; t < 5; ++t) {
#pragma unroll
            for (int i = 0; i < 4; ++i) {
                const int oc = (ocb0 + o) * 16 + rowL[i];
                double v = acc[o][t][i] + bias[oc];
                if (RELU) v = fmax(v, 0.0);
                out[(size_t)oc * PIX + y * WC + t * 16 + colL[i]] = v;
            }
        }
    }
}

// ---------------------------------------------------------------------------
// conv1x1 (128->65) + softmax(65)[:64] + pixel-unshuffle.  grid (19, G).
// ---------------------------------------------------------------------------
__global__ __launch_bounds__(256) void conv1x1_softmax_f64(
    const double* __restrict__ h2,   // [G][128][4800]
    const double* __restrict__ wg,   // [65][128]
    const double* __restrict__ bg,   // [65]
    double* __restrict__ S)          // [G][480][640]
{
    int p = blockIdx.x * 256 + threadIdx.x;
    if (p >= PIX) return;
    const int b = blockIdx.y;
    const double* h2p = h2 + (size_t)b * 128 * PIX + p;
    double* Sb = S + (size_t)b * IMG;

    double l[65];
#pragma unroll
    for (int o = 0; o < 65; ++o) l[o] = bg[o];

    for (int icc = 0; icc < 128; icc += 8) {
        double h[8];
#pragma unroll
        for (int k = 0; k < 8; ++k) h[k] = h2p[(size_t)(icc + k) * PIX];
#pragma unroll
        for (int o = 0; o < 65; ++o) {
            const double* wp = wg + o * 128 + icc;
            l[o] += h[0] * wp[0] + h[1] * wp[1] + h[2] * wp[2] + h[3] * wp[3]
                  + h[4] * wp[4] + h[5] * wp[5] + h[6] * wp[6] + h[7] * wp[7];
        }
    }

    double m = l[0];
#pragma unroll
    for (int o = 1; o < 65; ++o) m = fmax(m, l[o]);
    double s = 0.0;
#pragma unroll
    for (int o = 0; o < 65; ++o) { l[o] = exp(l[o] - m); s += l[o]; }
    double inv = 1.0 / s;

    int y = p / WC, x = p % WC;
#pragma unroll
    for (int cy = 0; cy < 8; ++cy)
#pragma unroll
        for (int cx2 = 0; cx2 < 8; ++cx2)
            Sb[(y * 8 + cy) * WF + x * 8 + cx2] = l[cy * 8 + cx2] * inv;
}

// ---------------------------------------------------------------------------
// NMS passes on f64 scores (equality decisions must be f64-exact).
// ---------------------------------------------------------------------------
__global__ __launch_bounds__(256) void hmax9_f64(const double* __restrict__ in,
                                                 double* __restrict__ out)
{
    int p = blockIdx.x * 256 + threadIdx.x;
    int x = p % WF;
    const double* row = in + (p - x);
    double m = row[x];
#pragma unroll
    for (int d = 1; d <= 4; ++d) {
        m = fmax(m, row[clampi(x - d, 0, WF - 1)]);
        m = fmax(m, row[clampi(x + d, 0, WF - 1)]);
    }
    out[p] = m;
}

__global__ __launch_bounds__(256) void vmax9_eq(const double* __restrict__ T,
                                                const double* __restrict__ S,
                                                unsigned char* __restrict__ M)
{
    int p = blockIdx.x * 256 + threadIdx.x;
    int y = (p % IMG) / WF;
    double m = T[p];
#pragma unroll
    for (int d = 1; d <= 4; ++d) {
        m = fmax(m, T[p + (clampi(y - d, 0, HF - 1) - y) * WF]);
        m = fmax(m, T[p + (clampi(y + d, 0, HF - 1) - y) * WF]);
    }
    M[p] = (S[p] == m) ? (unsigned char)1 : (unsigned char)0;
}

__global__ __launch_bounds__(256) void hor9_u8(const unsigned char* __restrict__ in,
                                               unsigned char* __restrict__ out)
{
    int p = blockIdx.x * 256 + threadIdx.x;
    int x = p % WF;
    const unsigned char* row = in + (p - x);
    unsigned char m = row[x];
#pragma unroll
    for (int d = 1; d <= 4; ++d) {
        m = m | row[clampi(x - d, 0, WF - 1)];
        m = m | row[clampi(x + d, 0, WF - 1)];
    }
    out[p] = m;
}

__global__ __launch_bounds__(256) void vor9_sup(const unsigned char* __restrict__ T8,
                                                unsigned char* __restrict__ SUP)
{
    int p = blockIdx.x * 256 + threadIdx.x;
    int y = (p % IMG) / WF;
    unsigned char m = T8[p];
#pragma unroll
    for (int d = 1; d <= 4; ++d) {
        m = m | T8[p + (clampi(y - d, 0, HF - 1) - y) * WF];
        m = m | T8[p + (clampi(y + d, 0, HF - 1) - y) * WF];
    }
    SUP[p] = m;
}

// horizontal max of (SUP ? 0 : S)
__global__ __launch_bounds__(256) void hmax9_supp(const double* __restrict__ S,
                                                  const unsigned char* __restrict__ SUP,
                                                  double* __restrict__ T)
{
    int p = blockIdx.x * 256 + threadIdx.x;
    int x = p % WF;
    int base = p - x;
    double m = SUP[p] ? 0.0 : S[p];
#pragma unroll
    for (int d = 1; d <= 4; ++d) {
        int i1 = base + clampi(x - d, 0, WF - 1);
        int i2 = base + clampi(x + d, 0, WF - 1);
        m = fmax(m, SUP[i1] ? 0.0 : S[i1]);
        m = fmax(m, SUP[i2] ? 0.0 : S[i2]);
    }
    T[p] = m;
}

__global__ __launch_bounds__(256) void vmax9_newmask(const double* __restrict__ T,
                                                     const double* __restrict__ S,
                                                     const unsigned char* __restrict__ SUP,
                                                     unsigned char* __restrict__ M)
{
    int p = blockIdx.x * 256 + threadIdx.x;
    int y = (p % IMG) / WF;
    double m = T[p];
#pragma unroll
    for (int d = 1; d <= 4; ++d) {
        m = fmax(m, T[p + (clampi(y - d, 0, HF - 1) - y) * WF]);
        m = fmax(m, T[p + (clampi(y + d, 0, HF - 1) - y) * WF]);
    }
    unsigned char nw = (!SUP[p] && S[p] == m) ? 1 : 0;
    M[p] = M[p] | nw;
}

__global__ __launch_bounds__(256) void final_mask(const double* __restrict__ S,
                                                  const unsigned char* __restrict__ M,
                                                  float* __restrict__ out)
{
    int p = blockIdx.x * 256 + threadIdx.x;
    out[p] = M[p] ? (float)S[p] : 0.f;
}

// ---------------------------------------------------------------------------
extern "C" void kernel_launch(void* const* d_in, const int* in_sizes, int n_in,
                              void* d_out, int out_size, void* d_ws, size_t ws_size,
                              hipStream_t stream)
{
    const float* x   = (const float*)d_in[0];
    const float* wPa = (const float*)d_in[1];
    const float* bPa = (const float*)d_in[2];
    const float* wPd = (const float*)d_in[3];
    const float* bPd = (const float*)d_in[4];
    const float* wPg = (const float*)d_in[5];
    const float* bPg = (const float*)d_in[6];
    float* out = (float*)d_out;

    char* ws = (char*)d_ws;
    // ---- persistent / NMS-phase layout -------------------------------------
    double*        S   = (double*)(ws);                        // 39,321,600
    double*        T   = (double*)(ws + 39321600);             // 39,321,600
    unsigned char* M   = (unsigned char*)(ws + 78643200);      //  4,915,200
    unsigned char* SUP = (unsigned char*)(ws + 83558400);      //  4,915,200
    unsigned char* T8  = (unsigned char*)(ws + 88473600);      //  4,915,200
    // ---- conv-phase overlay (inside T region, dead until NMS) --------------
    double* w1t = (double*)(ws + 39321600);   // 256*512*9*8 = 9,437,184 (transformed)
    double* w2t = (double*)(ws + 48758784);   // 128*256*9*8 = 2,359,296 (transformed)
    double* wgd = (double*)(ws + 51118080);   // 65*128*8    =    66,560
    double* b1d = (double*)(ws + 51184640);   // 2,048
    double* b2d = (double*)(ws + 51186688);   // 1,024
    double* bgd = (double*)(ws + 51187712);   // 1,024 (pad)
    char*   hbase = ws + 51188736;            // batch-group h1/h2 area

    // largest batch-group G with 51,188,736 + G*14,745,600 <= ws_size
    // (G=16 confirmed on hardware in rounds 3-11)
    int G = 1;
    for (int g = 16; g >= 1; g >>= 1) {
        if ((size_t)51188736 + (size_t)g * 14745600 <= ws_size) { G = g; break; }
    }

    // weights -> f64, mfma layout for 3x3 convs
    prep_w<<<(1179648 + 255) / 256, 256, 0, stream>>>(wPa, w1t, 512, 1179648);
    prep_w<<<(294912 + 255) / 256, 256, 0, stream>>>(wPd, w2t, 256, 294912);
    cvt_f32_f64<<<(8320 + 255) / 256, 256, 0, stream>>>(wPg, wgd, 8320);
    cvt_f32_f64<<<1, 256, 0, stream>>>(bPa, b1d, 256);
    cvt_f32_f64<<<1, 256, 0, stream>>>(bPd, b2d, 128);
    cvt_f32_f64<<<1, 256, 0, stream>>>(bPg, bgd, 65);

    for (int bg0 = 0; bg0 < B_; bg0 += G) {
        int Gc = (bg0 + G <= B_) ? G : (B_ - bg0);
        double* h1s = (double*)hbase;                              // Gc*256*4800 f64
        double* h2s = (double*)(hbase + (size_t)G * 9830400);      // Gc*128*4800 f64
        const float* xb = x + (size_t)bg0 * 512 * PIX;
        conv3x3_mfma<512, float, true><<<dim3(30, 4, Gc), 256, 0, stream>>>(xb, w1t, b1d, h1s);
        conv3x3_mfma<256, double, true><<<dim3(30, 2, Gc), 256, 0, stream>>>(h1s, w2t, b2d, h2s);
        conv1x1_softmax_f64<<<dim3(19, Gc), 256, 0, stream>>>(h2s, wgd, bgd, S + (size_t)bg0 * IMG);
    }

    const int NB = NPIX / 256;  // 19200
    hmax9_f64<<<NB, 256, 0, stream>>>(S, T);
    vmax9_eq<<<NB, 256, 0, stream>>>(T, S, M);
    for (int it = 0; it < 2; ++it) {
        hor9_u8<<<NB, 256, 0, stream>>>(M, T8);
        vor9_sup<<<NB, 256, 0, stream>>>(T8, SUP);
        hmax9_supp<<<NB, 256, 0, stream>>>(S, SUP, T);
        vmax9_newmask<<<NB, 256, 0, stream>>>(T, S, SUP, M);
    }
    final_mask<<<NB, 256, 0, stream>>>(S, M, out);
}